// Round 1
// baseline (944.777 us; speedup 1.0000x reference)
//
#include <hip/hip_runtime.h>
#include <hip/hip_bf16.h>
#include <cstdint>
#include <cstddef>

// ---------------------------------------------------------------------------
// StationGNN: 3x GraphSAGE(mean) layers + MLP head, all fp32.
// N=50000 nodes, E=800000 edges, feature dim 128 throughout, head 128->64->4.
// Strategy: build CSR (by dst) once per launch, then per layer:
//   mean[n] = (1/max(deg,1)) * sum_{s in nbrs(n)} x[s]      (wave per node)
//   out     = ReLU(mean @ Wl^T + x @ Wr^T + bl)             (fp32 LDS-tiled GEMM)
// Head: per-thread dot products (small).
// ---------------------------------------------------------------------------

__global__ void deg_count_kernel(const int* __restrict__ dst, int E,
                                 int* __restrict__ deg) {
    int e = blockIdx.x * 256 + threadIdx.x;
    if (e < E) atomicAdd(&deg[dst[e]], 1);
}

__global__ __launch_bounds__(1024) void scan_kernel(const int* __restrict__ deg, int N,
                                                    int* __restrict__ row_ptr,
                                                    int* __restrict__ cursor) {
    __shared__ int sdata[1024];
    __shared__ int carry_s;
    int tid = threadIdx.x;
    if (tid == 0) carry_s = 0;
    __syncthreads();
    for (int base = 0; base < N; base += 1024) {
        int idx = base + tid;
        int v = (idx < N) ? deg[idx] : 0;
        sdata[tid] = v;
        __syncthreads();
        for (int off = 1; off < 1024; off <<= 1) {
            int t = (tid >= off) ? sdata[tid - off] : 0;
            __syncthreads();
            sdata[tid] += t;
            __syncthreads();
        }
        int excl = sdata[tid] - v;   // exclusive scan within chunk
        int c = carry_s;             // read BEFORE update barrier
        if (idx < N) { row_ptr[idx] = c + excl; cursor[idx] = c + excl; }
        int tot = sdata[1023];
        __syncthreads();
        if (tid == 0) carry_s = c + tot;
        __syncthreads();
    }
    if (tid == 0) row_ptr[N] = carry_s;
}

__global__ void fill_kernel(const int* __restrict__ src, const int* __restrict__ dst,
                            int E, int* __restrict__ cursor, int* __restrict__ col) {
    int e = blockIdx.x * 256 + threadIdx.x;
    if (e < E) {
        int p = atomicAdd(&cursor[dst[e]], 1);
        col[p] = src[e];
    }
}

// one wave (64 lanes) per destination node; lane handles 2 features (float2)
__global__ __launch_bounds__(256) void agg_mean_kernel(const float* __restrict__ xin,
                                                       const int* __restrict__ row_ptr,
                                                       const int* __restrict__ col,
                                                       float* __restrict__ mean, int N) {
    int wave = threadIdx.x >> 6;
    int lane = threadIdx.x & 63;
    int n = blockIdx.x * 4 + wave;
    if (n >= N) return;
    int beg = row_ptr[n];
    int end = row_ptr[n + 1];
    float ax = 0.f, ay = 0.f;
    for (int i = beg; i < end; ++i) {
        int s = col[i];
        float2 v = ((const float2*)(xin + (size_t)s * 128))[lane];
        ax += v.x; ay += v.y;
    }
    int d = end - beg;
    float inv = 1.0f / (float)(d > 0 ? d : 1);
    float2 o; o.x = ax * inv; o.y = ay * inv;
    ((float2*)(mean + (size_t)n * 128))[lane] = o;
}

// out[n][j] = ReLU( sum_k A0[n][k]*W0[j][k] + sum_k A1[n][k]*W1[j][k] + bias[j] )
// Tile: 64 nodes x 128 outputs per 256-thread block; thread = 4 nodes x 8 outs.
__global__ __launch_bounds__(256) void sage_gemm_kernel(
    const float* __restrict__ A0, const float* __restrict__ A1,
    const float* __restrict__ W0, const float* __restrict__ W1,
    const float* __restrict__ bias, float* __restrict__ out, int N) {
    __shared__ float As[64][33];    // +1 pad: conflict-free scalar reads
    __shared__ float Bs[32][132];   // +4 pad: coalesced global, 4-way write conflict only
    int tid = threadIdx.x;
    int n0 = blockIdx.x * 64;
    int ti = tid & 15;      // node sub-tile (4 nodes)
    int tj = tid >> 4;      // output sub-tile (8 outs)

    float acc[4][8];
#pragma unroll
    for (int r = 0; r < 4; ++r)
#pragma unroll
        for (int c = 0; c < 8; ++c) acc[r][c] = 0.f;

    for (int part = 0; part < 2; ++part) {
        const float* A = part ? A1 : A0;
        const float* W = part ? W1 : W0;
        for (int kk = 0; kk < 128; kk += 32) {
            // stage A tile: [i][k], global reads coalesced along k
            int ks = tid & 31, i0 = tid >> 5;
#pragma unroll
            for (int r = 0; r < 8; ++r) {
                int i = i0 + 8 * r;
                int n = n0 + i;
                As[i][ks] = (n < N) ? A[(size_t)n * 128 + kk + ks] : 0.f;
            }
            // stage B tile: Bs[k][j] = W[j][kk+k], global reads coalesced along k
            int jj0 = tid >> 5;  // 0..7
#pragma unroll
            for (int r = 0; r < 16; ++r) {
                int j = jj0 + 8 * r;
                Bs[ks][j] = W[(size_t)j * 128 + kk + ks];
            }
            __syncthreads();
#pragma unroll 4
            for (int k = 0; k < 32; ++k) {
                float4 b0 = *(const float4*)&Bs[k][8 * tj];
                float4 b1 = *(const float4*)&Bs[k][8 * tj + 4];
#pragma unroll
                for (int r = 0; r < 4; ++r) {
                    float a = As[4 * ti + r][k];
                    acc[r][0] += a * b0.x; acc[r][1] += a * b0.y;
                    acc[r][2] += a * b0.z; acc[r][3] += a * b0.w;
                    acc[r][4] += a * b1.x; acc[r][5] += a * b1.y;
                    acc[r][6] += a * b1.z; acc[r][7] += a * b1.w;
                }
            }
            __syncthreads();
        }
    }
    // epilogue: bias + ReLU, float4 stores
    float4 bv0 = *(const float4*)&bias[8 * tj];
    float4 bv1 = *(const float4*)&bias[8 * tj + 4];
#pragma unroll
    for (int r = 0; r < 4; ++r) {
        int n = n0 + 4 * ti + r;
        if (n >= N) continue;
        float4 o0, o1;
        o0.x = fmaxf(acc[r][0] + bv0.x, 0.f);
        o0.y = fmaxf(acc[r][1] + bv0.y, 0.f);
        o0.z = fmaxf(acc[r][2] + bv0.z, 0.f);
        o0.w = fmaxf(acc[r][3] + bv0.w, 0.f);
        o1.x = fmaxf(acc[r][4] + bv1.x, 0.f);
        o1.y = fmaxf(acc[r][5] + bv1.y, 0.f);
        o1.z = fmaxf(acc[r][6] + bv1.z, 0.f);
        o1.w = fmaxf(acc[r][7] + bv1.w, 0.f);
        *(float4*)&out[(size_t)n * 128 + 8 * tj] = o0;
        *(float4*)&out[(size_t)n * 128 + 8 * tj + 4] = o1;
    }
}

// h1[n][j] = ReLU( dot128(h[n], Wh1[j]) + bh1[j] ),  j in [0,64)
__global__ void head1_kernel(const float* __restrict__ h, const float* __restrict__ Wh1,
                             const float* __restrict__ bh1, float* __restrict__ h1, int N) {
    int idx = blockIdx.x * 256 + threadIdx.x;
    if (idx >= N * 64) return;
    int n = idx >> 6, j = idx & 63;
    const float4* a = (const float4*)(h + (size_t)n * 128);
    const float4* w = (const float4*)(Wh1 + (size_t)j * 128);
    float s = 0.f;
#pragma unroll 8
    for (int k = 0; k < 32; ++k) {
        float4 av = a[k], wv = w[k];
        s += av.x * wv.x + av.y * wv.y + av.z * wv.z + av.w * wv.w;
    }
    h1[idx] = fmaxf(s + bh1[j], 0.f);
}

// out[n][c] = dot64(h1[n], Wh2[c]) + bh2[c],  c in [0,4)
__global__ void head2_kernel(const float* __restrict__ h1, const float* __restrict__ Wh2,
                             const float* __restrict__ bh2, float* __restrict__ out, int N) {
    int idx = blockIdx.x * 256 + threadIdx.x;
    if (idx >= N * 4) return;
    int n = idx >> 2, c = idx & 3;
    const float4* a = (const float4*)(h1 + (size_t)n * 64);
    const float4* w = (const float4*)(Wh2 + (size_t)c * 64);
    float s = bh2[c];
#pragma unroll
    for (int k = 0; k < 16; ++k) {
        float4 av = a[k], wv = w[k];
        s += av.x * wv.x + av.y * wv.y + av.z * wv.z + av.w * wv.w;
    }
    out[idx] = s;
}

extern "C" void kernel_launch(void* const* d_in, const int* in_sizes, int n_in,
                              void* d_out, int out_size, void* d_ws, size_t ws_size,
                              hipStream_t stream) {
    const float* x   = (const float*)d_in[0];
    const int*   ei  = (const int*)d_in[1];
    const float* Wl0 = (const float*)d_in[2];
    const float* bl0 = (const float*)d_in[3];
    const float* Wr0 = (const float*)d_in[4];
    const float* Wl1 = (const float*)d_in[5];
    const float* bl1 = (const float*)d_in[6];
    const float* Wr1 = (const float*)d_in[7];
    const float* Wl2 = (const float*)d_in[8];
    const float* bl2 = (const float*)d_in[9];
    const float* Wr2 = (const float*)d_in[10];
    const float* Wh1 = (const float*)d_in[11];
    const float* bh1 = (const float*)d_in[12];
    const float* Wh2 = (const float*)d_in[13];
    const float* bh2 = (const float*)d_in[14];
    float* out = (float*)d_out;

    const int N = in_sizes[0] / 128;
    const int E = in_sizes[1] / 2;
    const int* src = ei;
    const int* dst = ei + E;

    // workspace layout
    int* deg     = (int*)d_ws;          // N
    int* row_ptr = deg + N;             // N+1
    int* cursor  = row_ptr + N + 1;     // N
    int* col     = cursor + N;          // E
    size_t foff = (((size_t)(3 * N + 1 + E)) * sizeof(int) + 255) & ~(size_t)255;
    float* mean = (float*)((char*)d_ws + foff);        // N*128 (also reused as h1 N*64)
    float* hA   = mean + (size_t)N * 128;              // N*128
    float* hB   = hA + (size_t)N * 128;                // N*128

    const int eb = (E + 255) / 256;
    const int nb4 = (N + 3) / 4;
    const int gb = (N + 63) / 64;

    // CSR build
    hipMemsetAsync(deg, 0, (size_t)N * sizeof(int), stream);
    deg_count_kernel<<<eb, 256, 0, stream>>>(dst, E, deg);
    scan_kernel<<<1, 1024, 0, stream>>>(deg, N, row_ptr, cursor);
    fill_kernel<<<eb, 256, 0, stream>>>(src, dst, E, cursor, col);

    // layer 0
    agg_mean_kernel<<<nb4, 256, 0, stream>>>(x, row_ptr, col, mean, N);
    sage_gemm_kernel<<<gb, 256, 0, stream>>>(mean, x, Wl0, Wr0, bl0, hA, N);
    // layer 1
    agg_mean_kernel<<<nb4, 256, 0, stream>>>(hA, row_ptr, col, mean, N);
    sage_gemm_kernel<<<gb, 256, 0, stream>>>(mean, hA, Wl1, Wr1, bl1, hB, N);
    // layer 2
    agg_mean_kernel<<<nb4, 256, 0, stream>>>(hB, row_ptr, col, mean, N);
    sage_gemm_kernel<<<gb, 256, 0, stream>>>(mean, hB, Wl2, Wr2, bl2, hA, N);

    // head MLP: h1 = relu(hA @ Wh1^T + bh1) ; out = h1 @ Wh2^T + bh2
    head1_kernel<<<(N * 64 + 255) / 256, 256, 0, stream>>>(hA, Wh1, bh1, mean, N);
    head2_kernel<<<(N * 4 + 255) / 256, 256, 0, stream>>>(mean, Wh2, bh2, out, N);
}

// Round 2
// 677.643 us; speedup vs baseline: 1.3942x; 1.3942x over previous
//
#include <hip/hip_runtime.h>
#include <hip/hip_bf16.h>
#include <cstdint>
#include <cstddef>

// ---------------------------------------------------------------------------
// StationGNN: 3x GraphSAGE(mean) layers + MLP head, all fp32.
// R1: head1 (224us, latency-bound lane-gather of Wh1 rows) + head2 fused into
//     one LDS-tiled GEMM per 64-node block; agg_mean unrolled x2.
// ---------------------------------------------------------------------------

__global__ void deg_count_kernel(const int* __restrict__ dst, int E,
                                 int* __restrict__ deg) {
    int e = blockIdx.x * 256 + threadIdx.x;
    if (e < E) atomicAdd(&deg[dst[e]], 1);
}

__global__ __launch_bounds__(1024) void scan_kernel(const int* __restrict__ deg, int N,
                                                    int* __restrict__ row_ptr,
                                                    int* __restrict__ cursor) {
    __shared__ int sdata[1024];
    __shared__ int carry_s;
    int tid = threadIdx.x;
    if (tid == 0) carry_s = 0;
    __syncthreads();
    for (int base = 0; base < N; base += 1024) {
        int idx = base + tid;
        int v = (idx < N) ? deg[idx] : 0;
        sdata[tid] = v;
        __syncthreads();
        for (int off = 1; off < 1024; off <<= 1) {
            int t = (tid >= off) ? sdata[tid - off] : 0;
            __syncthreads();
            sdata[tid] += t;
            __syncthreads();
        }
        int excl = sdata[tid] - v;   // exclusive scan within chunk
        int c = carry_s;             // read BEFORE update barrier
        if (idx < N) { row_ptr[idx] = c + excl; cursor[idx] = c + excl; }
        int tot = sdata[1023];
        __syncthreads();
        if (tid == 0) carry_s = c + tot;
        __syncthreads();
    }
    if (tid == 0) row_ptr[N] = carry_s;
}

__global__ void fill_kernel(const int* __restrict__ src, const int* __restrict__ dst,
                            int E, int* __restrict__ cursor, int* __restrict__ col) {
    int e = blockIdx.x * 256 + threadIdx.x;
    if (e < E) {
        int p = atomicAdd(&cursor[dst[e]], 1);
        col[p] = src[e];
    }
}

// one wave (64 lanes) per destination node; lane handles 2 features (float2)
// unroll x2: two independent row-gathers in flight per iteration
__global__ __launch_bounds__(256) void agg_mean_kernel(const float* __restrict__ xin,
                                                       const int* __restrict__ row_ptr,
                                                       const int* __restrict__ col,
                                                       float* __restrict__ mean, int N) {
    int wave = threadIdx.x >> 6;
    int lane = threadIdx.x & 63;
    int n = blockIdx.x * 4 + wave;
    if (n >= N) return;
    int beg = row_ptr[n];
    int end = row_ptr[n + 1];
    float ax = 0.f, ay = 0.f, bx = 0.f, by = 0.f;
    int i = beg;
    for (; i + 1 < end; i += 2) {
        int s0 = col[i];
        int s1 = col[i + 1];
        float2 v0 = ((const float2*)(xin + (size_t)s0 * 128))[lane];
        float2 v1 = ((const float2*)(xin + (size_t)s1 * 128))[lane];
        ax += v0.x; ay += v0.y;
        bx += v1.x; by += v1.y;
    }
    if (i < end) {
        int s0 = col[i];
        float2 v0 = ((const float2*)(xin + (size_t)s0 * 128))[lane];
        ax += v0.x; ay += v0.y;
    }
    int d = end - beg;
    float inv = 1.0f / (float)(d > 0 ? d : 1);
    float2 o; o.x = (ax + bx) * inv; o.y = (ay + by) * inv;
    ((float2*)(mean + (size_t)n * 128))[lane] = o;
}

// out[n][j] = ReLU( sum_k A0[n][k]*W0[j][k] + sum_k A1[n][k]*W1[j][k] + bias[j] )
// Tile: 64 nodes x 128 outputs per 256-thread block; thread = 4 nodes x 8 outs.
__global__ __launch_bounds__(256) void sage_gemm_kernel(
    const float* __restrict__ A0, const float* __restrict__ A1,
    const float* __restrict__ W0, const float* __restrict__ W1,
    const float* __restrict__ bias, float* __restrict__ out, int N) {
    __shared__ float As[64][33];    // +1 pad: conflict-free scalar reads
    __shared__ float Bs[32][132];   // +4 pad
    int tid = threadIdx.x;
    int n0 = blockIdx.x * 64;
    int ti = tid & 15;      // node sub-tile (4 nodes)
    int tj = tid >> 4;      // output sub-tile (8 outs)

    float acc[4][8];
#pragma unroll
    for (int r = 0; r < 4; ++r)
#pragma unroll
        for (int c = 0; c < 8; ++c) acc[r][c] = 0.f;

    for (int part = 0; part < 2; ++part) {
        const float* A = part ? A1 : A0;
        const float* W = part ? W1 : W0;
        for (int kk = 0; kk < 128; kk += 32) {
            int ks = tid & 31, i0 = tid >> 5;
#pragma unroll
            for (int r = 0; r < 8; ++r) {
                int i = i0 + 8 * r;
                int n = n0 + i;
                As[i][ks] = (n < N) ? A[(size_t)n * 128 + kk + ks] : 0.f;
            }
            int jj0 = tid >> 5;  // 0..7
#pragma unroll
            for (int r = 0; r < 16; ++r) {
                int j = jj0 + 8 * r;
                Bs[ks][j] = W[(size_t)j * 128 + kk + ks];
            }
            __syncthreads();
#pragma unroll 4
            for (int k = 0; k < 32; ++k) {
                float4 b0 = *(const float4*)&Bs[k][8 * tj];
                float4 b1 = *(const float4*)&Bs[k][8 * tj + 4];
#pragma unroll
                for (int r = 0; r < 4; ++r) {
                    float a = As[4 * ti + r][k];
                    acc[r][0] += a * b0.x; acc[r][1] += a * b0.y;
                    acc[r][2] += a * b0.z; acc[r][3] += a * b0.w;
                    acc[r][4] += a * b1.x; acc[r][5] += a * b1.y;
                    acc[r][6] += a * b1.z; acc[r][7] += a * b1.w;
                }
            }
            __syncthreads();
        }
    }
    float4 bv0 = *(const float4*)&bias[8 * tj];
    float4 bv1 = *(const float4*)&bias[8 * tj + 4];
#pragma unroll
    for (int r = 0; r < 4; ++r) {
        int n = n0 + 4 * ti + r;
        if (n >= N) continue;
        float4 o0, o1;
        o0.x = fmaxf(acc[r][0] + bv0.x, 0.f);
        o0.y = fmaxf(acc[r][1] + bv0.y, 0.f);
        o0.z = fmaxf(acc[r][2] + bv0.z, 0.f);
        o0.w = fmaxf(acc[r][3] + bv0.w, 0.f);
        o1.x = fmaxf(acc[r][4] + bv1.x, 0.f);
        o1.y = fmaxf(acc[r][5] + bv1.y, 0.f);
        o1.z = fmaxf(acc[r][6] + bv1.z, 0.f);
        o1.w = fmaxf(acc[r][7] + bv1.w, 0.f);
        *(float4*)&out[(size_t)n * 128 + 8 * tj] = o0;
        *(float4*)&out[(size_t)n * 128 + 8 * tj + 4] = o1;
    }
}

// Fused head: h1 = ReLU(h @ Wh1^T + bh1) [64x64 tile in LDS], out = h1 @ Wh2^T + bh2.
// Block: 256 threads, 64 nodes. Phase 1 thread = 4 nodes x 4 outs. Phase 2 thread = 1 (node,c).
__global__ __launch_bounds__(256) void head_fused_kernel(
    const float* __restrict__ h, const float* __restrict__ Wh1,
    const float* __restrict__ bh1, const float* __restrict__ Wh2,
    const float* __restrict__ bh2, float* __restrict__ out, int N) {
    __shared__ float As[64][33];   // h tile, +1 pad
    __shared__ float Bs[32][65];   // Bs[k][j] = Wh1[j][kk+k], +1 pad (conflict-free writes)
    __shared__ float Hs[64][65];   // h1 tile
    int tid = threadIdx.x;
    int n0 = blockIdx.x * 64;
    int ti = tid & 15;     // 4 nodes
    int tj = tid >> 4;     // 4 outs (of 64)

    float acc[4][4];
#pragma unroll
    for (int r = 0; r < 4; ++r)
#pragma unroll
        for (int c = 0; c < 4; ++c) acc[r][c] = 0.f;

    for (int kk = 0; kk < 128; kk += 32) {
        int ks = tid & 31, i0 = tid >> 5;
#pragma unroll
        for (int r = 0; r < 8; ++r) {
            int i = i0 + 8 * r;
            int n = n0 + i;
            As[i][ks] = (n < N) ? h[(size_t)n * 128 + kk + ks] : 0.f;
        }
        int jj0 = tid >> 5;  // 0..7, j = jj0 + 8r covers 0..63
#pragma unroll
        for (int r = 0; r < 8; ++r) {
            int j = jj0 + 8 * r;
            Bs[ks][j] = Wh1[(size_t)j * 128 + kk + ks];
        }
        __syncthreads();
#pragma unroll 4
        for (int k = 0; k < 32; ++k) {
            float4 b = *(const float4*)&Bs[k][4 * tj];
#pragma unroll
            for (int r = 0; r < 4; ++r) {
                float a = As[4 * ti + r][k];
                acc[r][0] += a * b.x; acc[r][1] += a * b.y;
                acc[r][2] += a * b.z; acc[r][3] += a * b.w;
            }
        }
        __syncthreads();
    }
    // bias + ReLU into Hs
    float4 bv = *(const float4*)&bh1[4 * tj];
#pragma unroll
    for (int r = 0; r < 4; ++r) {
        int i = 4 * ti + r;
        Hs[i][4 * tj + 0] = fmaxf(acc[r][0] + bv.x, 0.f);
        Hs[i][4 * tj + 1] = fmaxf(acc[r][1] + bv.y, 0.f);
        Hs[i][4 * tj + 2] = fmaxf(acc[r][2] + bv.z, 0.f);
        Hs[i][4 * tj + 3] = fmaxf(acc[r][3] + bv.w, 0.f);
    }
    __syncthreads();
    // phase 2: thread -> (node = tid>>2, c = tid&3); dot64 from LDS
    int ni = tid >> 2;
    int c = tid & 3;
    const float* w = Wh2 + (size_t)c * 64;
    float s = bh2[c];
#pragma unroll 8
    for (int k = 0; k < 64; ++k) s += Hs[ni][k] * w[k];
    int n = n0 + ni;
    if (n < N) out[(size_t)n * 4 + c] = s;
}

extern "C" void kernel_launch(void* const* d_in, const int* in_sizes, int n_in,
                              void* d_out, int out_size, void* d_ws, size_t ws_size,
                              hipStream_t stream) {
    const float* x   = (const float*)d_in[0];
    const int*   ei  = (const int*)d_in[1];
    const float* Wl0 = (const float*)d_in[2];
    const float* bl0 = (const float*)d_in[3];
    const float* Wr0 = (const float*)d_in[4];
    const float* Wl1 = (const float*)d_in[5];
    const float* bl1 = (const float*)d_in[6];
    const float* Wr1 = (const float*)d_in[7];
    const float* Wl2 = (const float*)d_in[8];
    const float* bl2 = (const float*)d_in[9];
    const float* Wr2 = (const float*)d_in[10];
    const float* Wh1 = (const float*)d_in[11];
    const float* bh1 = (const float*)d_in[12];
    const float* Wh2 = (const float*)d_in[13];
    const float* bh2 = (const float*)d_in[14];
    float* out = (float*)d_out;

    const int N = in_sizes[0] / 128;
    const int E = in_sizes[1] / 2;
    const int* src = ei;
    const int* dst = ei + E;

    // workspace layout
    int* deg     = (int*)d_ws;          // N
    int* row_ptr = deg + N;             // N+1
    int* cursor  = row_ptr + N + 1;     // N
    int* col     = cursor + N;          // E
    size_t foff = (((size_t)(3 * N + 1 + E)) * sizeof(int) + 255) & ~(size_t)255;
    float* mean = (float*)((char*)d_ws + foff);        // N*128
    float* hA   = mean + (size_t)N * 128;              // N*128
    float* hB   = hA + (size_t)N * 128;                // N*128

    const int eb = (E + 255) / 256;
    const int nb4 = (N + 3) / 4;
    const int gb = (N + 63) / 64;

    // CSR build
    hipMemsetAsync(deg, 0, (size_t)N * sizeof(int), stream);
    deg_count_kernel<<<eb, 256, 0, stream>>>(dst, E, deg);
    scan_kernel<<<1, 1024, 0, stream>>>(deg, N, row_ptr, cursor);
    fill_kernel<<<eb, 256, 0, stream>>>(src, dst, E, cursor, col);

    // layer 0
    agg_mean_kernel<<<nb4, 256, 0, stream>>>(x, row_ptr, col, mean, N);
    sage_gemm_kernel<<<gb, 256, 0, stream>>>(mean, x, Wl0, Wr0, bl0, hA, N);
    // layer 1
    agg_mean_kernel<<<nb4, 256, 0, stream>>>(hA, row_ptr, col, mean, N);
    sage_gemm_kernel<<<gb, 256, 0, stream>>>(mean, hA, Wl1, Wr1, bl1, hB, N);
    // layer 2
    agg_mean_kernel<<<nb4, 256, 0, stream>>>(hB, row_ptr, col, mean, N);
    sage_gemm_kernel<<<gb, 256, 0, stream>>>(mean, hB, Wl2, Wr2, bl2, hA, N);

    // fused head MLP
    head_fused_kernel<<<gb, 256, 0, stream>>>(hA, Wh1, bh1, Wh2, bh2, out, N);
}

// Round 3
// 605.572 us; speedup vs baseline: 1.5601x; 1.1190x over previous
//
#include <hip/hip_runtime.h>
#include <hip/hip_bf16.h>
#include <cstdint>
#include <cstddef>

// ---------------------------------------------------------------------------
// StationGNN: 3x GraphSAGE(mean) layers + MLP head, all fp32.
// R1: fused head MLP (was 224us latency-bound gather).
// R2: parallel 3-phase scan (was 95us single-block serial scan, 0.18% occ).
// ---------------------------------------------------------------------------

__global__ void deg_count_kernel(const int* __restrict__ dst, int E,
                                 int* __restrict__ deg) {
    int e = blockIdx.x * 256 + threadIdx.x;
    if (e < E) atomicAdd(&deg[dst[e]], 1);
}

// phase 1: per-block (1024 elems) exclusive scan into row_ptr, block sum out
__global__ __launch_bounds__(1024) void scan_partial_kernel(const int* __restrict__ deg,
                                                            int N, int* __restrict__ excl,
                                                            int* __restrict__ blockSums) {
    __shared__ int sdata[1024];
    int tid = threadIdx.x;
    int idx = blockIdx.x * 1024 + tid;
    int v = (idx < N) ? deg[idx] : 0;
    sdata[tid] = v;
    __syncthreads();
    for (int off = 1; off < 1024; off <<= 1) {
        int t = (tid >= off) ? sdata[tid - off] : 0;
        __syncthreads();
        sdata[tid] += t;
        __syncthreads();
    }
    if (idx < N) excl[idx] = sdata[tid] - v;
    if (tid == 1023) blockSums[blockIdx.x] = sdata[1023];
}

// phase 2: serial exclusive scan of ~49 block sums (trivial)
__global__ void scan_sums_kernel(int* __restrict__ blockSums, int nb,
                                 int* __restrict__ row_ptr, int N) {
    if (threadIdx.x == 0 && blockIdx.x == 0) {
        int run = 0;
        for (int i = 0; i < nb; ++i) { int t = blockSums[i]; blockSums[i] = run; run += t; }
        row_ptr[N] = run;
    }
}

// phase 3: add block offsets in place; init cursor
__global__ void scan_add_kernel(int* __restrict__ row_ptr, int* __restrict__ cursor,
                                const int* __restrict__ blockSums, int N) {
    int idx = blockIdx.x * 256 + threadIdx.x;
    if (idx < N) {
        int v = row_ptr[idx] + blockSums[idx >> 10];
        row_ptr[idx] = v;
        cursor[idx] = v;
    }
}

__global__ void fill_kernel(const int* __restrict__ src, const int* __restrict__ dst,
                            int E, int* __restrict__ cursor, int* __restrict__ col) {
    int e = blockIdx.x * 256 + threadIdx.x;
    if (e < E) {
        int p = atomicAdd(&cursor[dst[e]], 1);
        col[p] = src[e];
    }
}

// one wave (64 lanes) per destination node; lane handles 2 features (float2)
// unroll x2: two independent row-gathers in flight per iteration
__global__ __launch_bounds__(256) void agg_mean_kernel(const float* __restrict__ xin,
                                                       const int* __restrict__ row_ptr,
                                                       const int* __restrict__ col,
                                                       float* __restrict__ mean, int N) {
    int wave = threadIdx.x >> 6;
    int lane = threadIdx.x & 63;
    int n = blockIdx.x * 4 + wave;
    if (n >= N) return;
    int beg = row_ptr[n];
    int end = row_ptr[n + 1];
    float ax = 0.f, ay = 0.f, bx = 0.f, by = 0.f;
    int i = beg;
    for (; i + 1 < end; i += 2) {
        int s0 = col[i];
        int s1 = col[i + 1];
        float2 v0 = ((const float2*)(xin + (size_t)s0 * 128))[lane];
        float2 v1 = ((const float2*)(xin + (size_t)s1 * 128))[lane];
        ax += v0.x; ay += v0.y;
        bx += v1.x; by += v1.y;
    }
    if (i < end) {
        int s0 = col[i];
        float2 v0 = ((const float2*)(xin + (size_t)s0 * 128))[lane];
        ax += v0.x; ay += v0.y;
    }
    int d = end - beg;
    float inv = 1.0f / (float)(d > 0 ? d : 1);
    float2 o; o.x = (ax + bx) * inv; o.y = (ay + by) * inv;
    ((float2*)(mean + (size_t)n * 128))[lane] = o;
}

// out[n][j] = ReLU( sum_k A0[n][k]*W0[j][k] + sum_k A1[n][k]*W1[j][k] + bias[j] )
// Tile: 64 nodes x 128 outputs per 256-thread block; thread = 4 nodes x 8 outs.
__global__ __launch_bounds__(256) void sage_gemm_kernel(
    const float* __restrict__ A0, const float* __restrict__ A1,
    const float* __restrict__ W0, const float* __restrict__ W1,
    const float* __restrict__ bias, float* __restrict__ out, int N) {
    __shared__ float As[64][33];    // +1 pad: conflict-free scalar reads
    __shared__ float Bs[32][132];   // +4 pad
    int tid = threadIdx.x;
    int n0 = blockIdx.x * 64;
    int ti = tid & 15;      // node sub-tile (4 nodes)
    int tj = tid >> 4;      // output sub-tile (8 outs)

    float acc[4][8];
#pragma unroll
    for (int r = 0; r < 4; ++r)
#pragma unroll
        for (int c = 0; c < 8; ++c) acc[r][c] = 0.f;

    for (int part = 0; part < 2; ++part) {
        const float* A = part ? A1 : A0;
        const float* W = part ? W1 : W0;
        for (int kk = 0; kk < 128; kk += 32) {
            int ks = tid & 31, i0 = tid >> 5;
#pragma unroll
            for (int r = 0; r < 8; ++r) {
                int i = i0 + 8 * r;
                int n = n0 + i;
                As[i][ks] = (n < N) ? A[(size_t)n * 128 + kk + ks] : 0.f;
            }
            int jj0 = tid >> 5;  // 0..7
#pragma unroll
            for (int r = 0; r < 16; ++r) {
                int j = jj0 + 8 * r;
                Bs[ks][j] = W[(size_t)j * 128 + kk + ks];
            }
            __syncthreads();
#pragma unroll 4
            for (int k = 0; k < 32; ++k) {
                float4 b0 = *(const float4*)&Bs[k][8 * tj];
                float4 b1 = *(const float4*)&Bs[k][8 * tj + 4];
#pragma unroll
                for (int r = 0; r < 4; ++r) {
                    float a = As[4 * ti + r][k];
                    acc[r][0] += a * b0.x; acc[r][1] += a * b0.y;
                    acc[r][2] += a * b0.z; acc[r][3] += a * b0.w;
                    acc[r][4] += a * b1.x; acc[r][5] += a * b1.y;
                    acc[r][6] += a * b1.z; acc[r][7] += a * b1.w;
                }
            }
            __syncthreads();
        }
    }
    float4 bv0 = *(const float4*)&bias[8 * tj];
    float4 bv1 = *(const float4*)&bias[8 * tj + 4];
#pragma unroll
    for (int r = 0; r < 4; ++r) {
        int n = n0 + 4 * ti + r;
        if (n >= N) continue;
        float4 o0, o1;
        o0.x = fmaxf(acc[r][0] + bv0.x, 0.f);
        o0.y = fmaxf(acc[r][1] + bv0.y, 0.f);
        o0.z = fmaxf(acc[r][2] + bv0.z, 0.f);
        o0.w = fmaxf(acc[r][3] + bv0.w, 0.f);
        o1.x = fmaxf(acc[r][4] + bv1.x, 0.f);
        o1.y = fmaxf(acc[r][5] + bv1.y, 0.f);
        o1.z = fmaxf(acc[r][6] + bv1.z, 0.f);
        o1.w = fmaxf(acc[r][7] + bv1.w, 0.f);
        *(float4*)&out[(size_t)n * 128 + 8 * tj] = o0;
        *(float4*)&out[(size_t)n * 128 + 8 * tj + 4] = o1;
    }
}

// Fused head: h1 = ReLU(h @ Wh1^T + bh1) [64x64 tile in LDS], out = h1 @ Wh2^T + bh2.
__global__ __launch_bounds__(256) void head_fused_kernel(
    const float* __restrict__ h, const float* __restrict__ Wh1,
    const float* __restrict__ bh1, const float* __restrict__ Wh2,
    const float* __restrict__ bh2, float* __restrict__ out, int N) {
    __shared__ float As[64][33];   // h tile, +1 pad
    __shared__ float Bs[32][65];   // Bs[k][j] = Wh1[j][kk+k]
    __shared__ float Hs[64][65];   // h1 tile
    int tid = threadIdx.x;
    int n0 = blockIdx.x * 64;
    int ti = tid & 15;     // 4 nodes
    int tj = tid >> 4;     // 4 outs (of 64)

    float acc[4][4];
#pragma unroll
    for (int r = 0; r < 4; ++r)
#pragma unroll
        for (int c = 0; c < 4; ++c) acc[r][c] = 0.f;

    for (int kk = 0; kk < 128; kk += 32) {
        int ks = tid & 31, i0 = tid >> 5;
#pragma unroll
        for (int r = 0; r < 8; ++r) {
            int i = i0 + 8 * r;
            int n = n0 + i;
            As[i][ks] = (n < N) ? h[(size_t)n * 128 + kk + ks] : 0.f;
        }
        int jj0 = tid >> 5;
#pragma unroll
        for (int r = 0; r < 8; ++r) {
            int j = jj0 + 8 * r;
            Bs[ks][j] = Wh1[(size_t)j * 128 + kk + ks];
        }
        __syncthreads();
#pragma unroll 4
        for (int k = 0; k < 32; ++k) {
            float4 b = *(const float4*)&Bs[k][4 * tj];
#pragma unroll
            for (int r = 0; r < 4; ++r) {
                float a = As[4 * ti + r][k];
                acc[r][0] += a * b.x; acc[r][1] += a * b.y;
                acc[r][2] += a * b.z; acc[r][3] += a * b.w;
            }
        }
        __syncthreads();
    }
    float4 bv = *(const float4*)&bh1[4 * tj];
#pragma unroll
    for (int r = 0; r < 4; ++r) {
        int i = 4 * ti + r;
        Hs[i][4 * tj + 0] = fmaxf(acc[r][0] + bv.x, 0.f);
        Hs[i][4 * tj + 1] = fmaxf(acc[r][1] + bv.y, 0.f);
        Hs[i][4 * tj + 2] = fmaxf(acc[r][2] + bv.z, 0.f);
        Hs[i][4 * tj + 3] = fmaxf(acc[r][3] + bv.w, 0.f);
    }
    __syncthreads();
    int ni = tid >> 2;
    int c = tid & 3;
    const float* w = Wh2 + (size_t)c * 64;
    float s = bh2[c];
#pragma unroll 8
    for (int k = 0; k < 64; ++k) s += Hs[ni][k] * w[k];
    int n = n0 + ni;
    if (n < N) out[(size_t)n * 4 + c] = s;
}

extern "C" void kernel_launch(void* const* d_in, const int* in_sizes, int n_in,
                              void* d_out, int out_size, void* d_ws, size_t ws_size,
                              hipStream_t stream) {
    const float* x   = (const float*)d_in[0];
    const int*   ei  = (const int*)d_in[1];
    const float* Wl0 = (const float*)d_in[2];
    const float* bl0 = (const float*)d_in[3];
    const float* Wr0 = (const float*)d_in[4];
    const float* Wl1 = (const float*)d_in[5];
    const float* bl1 = (const float*)d_in[6];
    const float* Wr1 = (const float*)d_in[7];
    const float* Wl2 = (const float*)d_in[8];
    const float* bl2 = (const float*)d_in[9];
    const float* Wr2 = (const float*)d_in[10];
    const float* Wh1 = (const float*)d_in[11];
    const float* bh1 = (const float*)d_in[12];
    const float* Wh2 = (const float*)d_in[13];
    const float* bh2 = (const float*)d_in[14];
    float* out = (float*)d_out;

    const int N = in_sizes[0] / 128;
    const int E = in_sizes[1] / 2;
    const int* src = ei;
    const int* dst = ei + E;

    // workspace layout
    int* deg       = (int*)d_ws;            // N
    int* row_ptr   = deg + N;               // N+1
    int* cursor    = row_ptr + N + 1;       // N
    int* blockSums = cursor + N;            // <= 64
    int* col       = blockSums + 64;        // E
    size_t foff = (((size_t)(3 * N + 1 + 64 + E)) * sizeof(int) + 255) & ~(size_t)255;
    float* mean = (float*)((char*)d_ws + foff);        // N*128
    float* hA   = mean + (size_t)N * 128;              // N*128
    float* hB   = hA + (size_t)N * 128;                // N*128

    const int eb = (E + 255) / 256;
    const int nb4 = (N + 3) / 4;
    const int gb = (N + 63) / 64;
    const int sb = (N + 1023) / 1024;       // scan blocks

    // CSR build
    hipMemsetAsync(deg, 0, (size_t)N * sizeof(int), stream);
    deg_count_kernel<<<eb, 256, 0, stream>>>(dst, E, deg);
    scan_partial_kernel<<<sb, 1024, 0, stream>>>(deg, N, row_ptr, blockSums);
    scan_sums_kernel<<<1, 64, 0, stream>>>(blockSums, sb, row_ptr, N);
    scan_add_kernel<<<(N + 255) / 256, 256, 0, stream>>>(row_ptr, cursor, blockSums, N);
    fill_kernel<<<eb, 256, 0, stream>>>(src, dst, E, cursor, col);

    // layer 0
    agg_mean_kernel<<<nb4, 256, 0, stream>>>(x, row_ptr, col, mean, N);
    sage_gemm_kernel<<<gb, 256, 0, stream>>>(mean, x, Wl0, Wr0, bl0, hA, N);
    // layer 1
    agg_mean_kernel<<<nb4, 256, 0, stream>>>(hA, row_ptr, col, mean, N);
    sage_gemm_kernel<<<gb, 256, 0, stream>>>(mean, hA, Wl1, Wr1, bl1, hB, N);
    // layer 2
    agg_mean_kernel<<<nb4, 256, 0, stream>>>(hB, row_ptr, col, mean, N);
    sage_gemm_kernel<<<gb, 256, 0, stream>>>(mean, hB, Wl2, Wr2, bl2, hA, N);

    // fused head MLP
    head_fused_kernel<<<gb, 256, 0, stream>>>(hA, Wh1, bh1, Wh2, bh2, out, N);
}

// Round 4
// 496.953 us; speedup vs baseline: 1.9011x; 1.2186x over previous
//
#include <hip/hip_runtime.h>
#include <cstdint>
#include <cstddef>

// ---------------------------------------------------------------------------
// StationGNN: 3x GraphSAGE(mean) + MLP head.
// R1: fused head MLP. R2: parallel scan.
// R3: split-bf16 (hi+lo) MFMA GEMM for the 3 SAGE layers. All feature
//     matrices stored as (hi,lo) bf16 pairs; conversion amortized in
//     memory-bound producers. 3-product MFMA gives ~2^-16 relative accuracy.
// ---------------------------------------------------------------------------

typedef __attribute__((ext_vector_type(8))) short short8;
typedef __attribute__((ext_vector_type(8))) unsigned short ushort8;
typedef __attribute__((ext_vector_type(4))) float floatx4;

__device__ __forceinline__ float bf2f(unsigned short h) {
    return __uint_as_float(((unsigned int)h) << 16);
}
// truncation split: x ~= hi + lo with |x-hi-lo| <~ 2^-16 |x|
__device__ __forceinline__ void split2(float x, unsigned short& hi, unsigned short& lo) {
    unsigned int u = __float_as_uint(x);
    hi = (unsigned short)(u >> 16);
    float r = x - __uint_as_float(u & 0xFFFF0000u);
    lo = (unsigned short)(__float_as_uint(r) >> 16);
}

// ------------------------------ CSR build ----------------------------------

__global__ void deg_count_kernel(const int* __restrict__ dst, int E,
                                 int* __restrict__ deg) {
    int e = blockIdx.x * 256 + threadIdx.x;
    if (e < E) atomicAdd(&deg[dst[e]], 1);
}

__global__ __launch_bounds__(1024) void scan_partial_kernel(const int* __restrict__ deg,
                                                            int N, int* __restrict__ excl,
                                                            int* __restrict__ blockSums) {
    __shared__ int sdata[1024];
    int tid = threadIdx.x;
    int idx = blockIdx.x * 1024 + tid;
    int v = (idx < N) ? deg[idx] : 0;
    sdata[tid] = v;
    __syncthreads();
    for (int off = 1; off < 1024; off <<= 1) {
        int t = (tid >= off) ? sdata[tid - off] : 0;
        __syncthreads();
        sdata[tid] += t;
        __syncthreads();
    }
    if (idx < N) excl[idx] = sdata[tid] - v;
    if (tid == 1023) blockSums[blockIdx.x] = sdata[1023];
}

__global__ void scan_sums_kernel(int* __restrict__ blockSums, int nb,
                                 int* __restrict__ row_ptr, int N) {
    if (threadIdx.x == 0 && blockIdx.x == 0) {
        int run = 0;
        for (int i = 0; i < nb; ++i) { int t = blockSums[i]; blockSums[i] = run; run += t; }
        row_ptr[N] = run;
    }
}

__global__ void scan_add_kernel(int* __restrict__ row_ptr, int* __restrict__ cursor,
                                const int* __restrict__ blockSums, int N) {
    int idx = blockIdx.x * 256 + threadIdx.x;
    if (idx < N) {
        int v = row_ptr[idx] + blockSums[idx >> 10];
        row_ptr[idx] = v;
        cursor[idx] = v;
    }
}

__global__ void fill_kernel(const int* __restrict__ src, const int* __restrict__ dst,
                            int E, int* __restrict__ cursor, int* __restrict__ col) {
    int e = blockIdx.x * 256 + threadIdx.x;
    if (e < E) {
        int p = atomicAdd(&cursor[dst[e]], 1);
        col[p] = src[e];
    }
}

// --------------------------- fp32 -> (hi,lo) -------------------------------

__global__ void convert_x_kernel(const float* __restrict__ x,
                                 unsigned short* __restrict__ xH,
                                 unsigned short* __restrict__ xL, int total4) {
    int i = blockIdx.x * 256 + threadIdx.x;
    if (i >= total4) return;
    float4 v = ((const float4*)x)[i];
    unsigned short h0, h1, h2, h3, l0, l1, l2, l3;
    split2(v.x, h0, l0); split2(v.y, h1, l1); split2(v.z, h2, l2); split2(v.w, h3, l3);
    ((ushort4*)xH)[i] = make_ushort4(h0, h1, h2, h3);
    ((ushort4*)xL)[i] = make_ushort4(l0, l1, l2, l3);
}

// 6 weight matrices (128x128 each): Wl0,Wr0,Wl1,Wr1,Wl2,Wr2 -> segments of WH/WL
__global__ void convert_w_kernel(const float* __restrict__ w0, const float* __restrict__ w1,
                                 const float* __restrict__ w2, const float* __restrict__ w3,
                                 const float* __restrict__ w4, const float* __restrict__ w5,
                                 unsigned short* __restrict__ WH,
                                 unsigned short* __restrict__ WL) {
    int m = blockIdx.y;
    const float* src = (m == 0) ? w0 : (m == 1) ? w1 : (m == 2) ? w2
                       : (m == 3) ? w3 : (m == 4) ? w4 : w5;
    int i = blockIdx.x * 256 + threadIdx.x;       // float4 index, 4096 per matrix
    if (i >= 4096) return;
    float4 v = ((const float4*)src)[i];
    unsigned short h0, h1, h2, h3, l0, l1, l2, l3;
    split2(v.x, h0, l0); split2(v.y, h1, l1); split2(v.z, h2, l2); split2(v.w, h3, l3);
    ((ushort4*)(WH + (size_t)m * 16384))[i] = make_ushort4(h0, h1, h2, h3);
    ((ushort4*)(WL + (size_t)m * 16384))[i] = make_ushort4(l0, l1, l2, l3);
}

// ------------------------------ aggregation --------------------------------
// one wave per node; lane covers 2 features; gathers (hi,lo) pairs,
// reconstructs fp32, writes mean as (hi,lo) pairs.
__global__ __launch_bounds__(256) void agg_mean_kernel(
    const unsigned short* __restrict__ inH, const unsigned short* __restrict__ inL,
    const int* __restrict__ row_ptr, const int* __restrict__ col,
    unsigned short* __restrict__ mH, unsigned short* __restrict__ mL, int N) {
    int wave = threadIdx.x >> 6;
    int lane = threadIdx.x & 63;
    int n = blockIdx.x * 4 + wave;
    if (n >= N) return;
    int beg = row_ptr[n];
    int end = row_ptr[n + 1];
    float ax = 0.f, ay = 0.f, bx = 0.f, by = 0.f;
    int i = beg;
    for (; i + 1 < end; i += 2) {
        int s0 = col[i];
        int s1 = col[i + 1];
        ushort2 h0 = ((const ushort2*)(inH + (size_t)s0 * 128))[lane];
        ushort2 g0 = ((const ushort2*)(inL + (size_t)s0 * 128))[lane];
        ushort2 h1 = ((const ushort2*)(inH + (size_t)s1 * 128))[lane];
        ushort2 g1 = ((const ushort2*)(inL + (size_t)s1 * 128))[lane];
        ax += bf2f(h0.x) + bf2f(g0.x); ay += bf2f(h0.y) + bf2f(g0.y);
        bx += bf2f(h1.x) + bf2f(g1.x); by += bf2f(h1.y) + bf2f(g1.y);
    }
    if (i < end) {
        int s0 = col[i];
        ushort2 h0 = ((const ushort2*)(inH + (size_t)s0 * 128))[lane];
        ushort2 g0 = ((const ushort2*)(inL + (size_t)s0 * 128))[lane];
        ax += bf2f(h0.x) + bf2f(g0.x); ay += bf2f(h0.y) + bf2f(g0.y);
    }
    int d = end - beg;
    float inv = 1.0f / (float)(d > 0 ? d : 1);
    float vx = (ax + bx) * inv, vy = (ay + by) * inv;
    unsigned short hx, lx, hy, ly;
    split2(vx, hx, lx); split2(vy, hy, ly);
    ((ushort2*)(mH + (size_t)n * 128))[lane] = make_ushort2(hx, hy);
    ((ushort2*)(mL + (size_t)n * 128))[lane] = make_ushort2(lx, ly);
}

// ------------------------- split-bf16 MFMA GEMM ----------------------------
// out[n][j] = ReLU( sum_k A0[n][k] W0[j][k] + A1[n][k] W1[j][k] + bias[j] )
// 128 nodes x 128 outs per 256-thread block; 4 waves = 2x2 quadrants of 64x64.
// 16x16x32 bf16 MFMA; A-frag: A[m=lane&15][k=quad*8+j]; B-frag symmetric;
// C/D: col=lane&15, row=quad*4+reg (verified layouts, guide §3).
__global__ __launch_bounds__(256, 2) void sage_gemm_mfma(
    const unsigned short* __restrict__ a0H, const unsigned short* __restrict__ a0L,
    const unsigned short* __restrict__ a1H, const unsigned short* __restrict__ a1L,
    const unsigned short* __restrict__ w0H, const unsigned short* __restrict__ w0L,
    const unsigned short* __restrict__ w1H, const unsigned short* __restrict__ w1L,
    const float* __restrict__ bias,
    unsigned short* __restrict__ outH, unsigned short* __restrict__ outL, int N) {
    __shared__ unsigned short Ah[128][40];   // stride 40 ushorts = 80B (16B-aligned rows)
    __shared__ unsigned short Al[128][40];
    __shared__ unsigned short Wh[128][40];
    __shared__ unsigned short Wl[128][40];
    int tid = threadIdx.x;
    int n0 = blockIdx.x * 128;
    int wv = tid >> 6, lane = tid & 63;
    int wm = wv & 1, wn = wv >> 1;           // wave quadrant
    int r16 = lane & 15, q = lane >> 4, q8 = q * 8;

    floatx4 acc[4][4];
#pragma unroll
    for (int mi = 0; mi < 4; ++mi)
#pragma unroll
        for (int ni = 0; ni < 4; ++ni) {
            floatx4 z = {0.f, 0.f, 0.f, 0.f};
            acc[mi][ni] = z;
        }

    int tc = (tid & 3) * 8;       // ushort column offset (4 chunks of 8)
    int tr = tid >> 2;            // 0..63 (rows tr, tr+64)

    for (int part = 0; part < 2; ++part) {
        const unsigned short* AH = part ? a1H : a0H;
        const unsigned short* AL = part ? a1L : a0L;
        const unsigned short* WHp = part ? w1H : w0H;
        const unsigned short* WLp = part ? w1L : w0L;
        for (int kk = 0; kk < 128; kk += 32) {
            __syncthreads();   // protect LDS from previous iteration's readers
#pragma unroll
            for (int rr = 0; rr < 2; ++rr) {
                int row = tr + 64 * rr;
                int n = n0 + row;
                ushort8 vh = {0, 0, 0, 0, 0, 0, 0, 0};
                ushort8 vl = {0, 0, 0, 0, 0, 0, 0, 0};
                if (n < N) {
                    vh = *(const ushort8*)&AH[(size_t)n * 128 + kk + tc];
                    vl = *(const ushort8*)&AL[(size_t)n * 128 + kk + tc];
                }
                *(ushort8*)&Ah[row][tc] = vh;
                *(ushort8*)&Al[row][tc] = vl;
                *(ushort8*)&Wh[row][tc] = *(const ushort8*)&WHp[(size_t)row * 128 + kk + tc];
                *(ushort8*)&Wl[row][tc] = *(const ushort8*)&WLp[(size_t)row * 128 + kk + tc];
            }
            __syncthreads();
            short8 ah[4], al[4];
#pragma unroll
            for (int mi = 0; mi < 4; ++mi) {
                int row = 64 * wm + 16 * mi + r16;
                ah[mi] = *(const short8*)&Ah[row][q8];
                al[mi] = *(const short8*)&Al[row][q8];
            }
#pragma unroll
            for (int ni = 0; ni < 4; ++ni) {
                int row = 64 * wn + 16 * ni + r16;
                short8 bh = *(const short8*)&Wh[row][q8];
                short8 bl = *(const short8*)&Wl[row][q8];
#pragma unroll
                for (int mi = 0; mi < 4; ++mi) {
                    acc[mi][ni] = __builtin_amdgcn_mfma_f32_16x16x32_bf16(ah[mi], bh, acc[mi][ni], 0, 0, 0);
                    acc[mi][ni] = __builtin_amdgcn_mfma_f32_16x16x32_bf16(al[mi], bh, acc[mi][ni], 0, 0, 0);
                    acc[mi][ni] = __builtin_amdgcn_mfma_f32_16x16x32_bf16(ah[mi], bl, acc[mi][ni], 0, 0, 0);
                }
            }
        }
    }
    // epilogue: bias + ReLU, split to (hi,lo)
#pragma unroll
    for (int ni = 0; ni < 4; ++ni) {
        int j = 64 * wn + 16 * ni + r16;
        float b = bias[j];
#pragma unroll
        for (int mi = 0; mi < 4; ++mi) {
            floatx4 v = acc[mi][ni];
#pragma unroll
            for (int p = 0; p < 4; ++p) {
                int node = n0 + 64 * wm + 16 * mi + 4 * q + p;
                if (node < N) {
                    float val = fmaxf(v[p] + b, 0.f);
                    unsigned short hi, lo;
                    split2(val, hi, lo);
                    outH[(size_t)node * 128 + j] = hi;
                    outL[(size_t)node * 128 + j] = lo;
                }
            }
        }
    }
}

// ------------------------------ fused head ---------------------------------
__global__ __launch_bounds__(256) void head_fused_kernel(
    const unsigned short* __restrict__ hH, const unsigned short* __restrict__ hL,
    const float* __restrict__ Wh1, const float* __restrict__ bh1,
    const float* __restrict__ Wh2, const float* __restrict__ bh2,
    float* __restrict__ out, int N) {
    __shared__ float As[64][33];
    __shared__ float Bs[32][65];
    __shared__ float Hs[64][65];
    int tid = threadIdx.x;
    int n0 = blockIdx.x * 64;
    int ti = tid & 15;
    int tj = tid >> 4;

    float acc[4][4];
#pragma unroll
    for (int r = 0; r < 4; ++r)
#pragma unroll
        for (int c = 0; c < 4; ++c) acc[r][c] = 0.f;

    for (int kk = 0; kk < 128; kk += 32) {
        int ks = tid & 31, i0 = tid >> 5;
#pragma unroll
        for (int r = 0; r < 8; ++r) {
            int i = i0 + 8 * r;
            int n = n0 + i;
            As[i][ks] = (n < N)
                ? (bf2f(hH[(size_t)n * 128 + kk + ks]) + bf2f(hL[(size_t)n * 128 + kk + ks]))
                : 0.f;
        }
        int jj0 = tid >> 5;
#pragma unroll
        for (int r = 0; r < 8; ++r) {
            int j = jj0 + 8 * r;
            Bs[ks][j] = Wh1[(size_t)j * 128 + kk + ks];
        }
        __syncthreads();
#pragma unroll 4
        for (int k = 0; k < 32; ++k) {
            float4 b = *(const float4*)&Bs[k][4 * tj];
#pragma unroll
            for (int r = 0; r < 4; ++r) {
                float a = As[4 * ti + r][k];
                acc[r][0] += a * b.x; acc[r][1] += a * b.y;
                acc[r][2] += a * b.z; acc[r][3] += a * b.w;
            }
        }
        __syncthreads();
    }
    float4 bv = *(const float4*)&bh1[4 * tj];
#pragma unroll
    for (int r = 0; r < 4; ++r) {
        int i = 4 * ti + r;
        Hs[i][4 * tj + 0] = fmaxf(acc[r][0] + bv.x, 0.f);
        Hs[i][4 * tj + 1] = fmaxf(acc[r][1] + bv.y, 0.f);
        Hs[i][4 * tj + 2] = fmaxf(acc[r][2] + bv.z, 0.f);
        Hs[i][4 * tj + 3] = fmaxf(acc[r][3] + bv.w, 0.f);
    }
    __syncthreads();
    int ni = tid >> 2;
    int c = tid & 3;
    const float* w = Wh2 + (size_t)c * 64;
    float s = bh2[c];
#pragma unroll 8
    for (int k = 0; k < 64; ++k) s += Hs[ni][k] * w[k];
    int n = n0 + ni;
    if (n < N) out[(size_t)n * 4 + c] = s;
}

// ------------------------------- launcher ----------------------------------

extern "C" void kernel_launch(void* const* d_in, const int* in_sizes, int n_in,
                              void* d_out, int out_size, void* d_ws, size_t ws_size,
                              hipStream_t stream) {
    const float* x   = (const float*)d_in[0];
    const int*   ei  = (const int*)d_in[1];
    const float* Wl0 = (const float*)d_in[2];
    const float* bl0 = (const float*)d_in[3];
    const float* Wr0 = (const float*)d_in[4];
    const float* Wl1 = (const float*)d_in[5];
    const float* bl1 = (const float*)d_in[6];
    const float* Wr1 = (const float*)d_in[7];
    const float* Wl2 = (const float*)d_in[8];
    const float* bl2 = (const float*)d_in[9];
    const float* Wr2 = (const float*)d_in[10];
    const float* Wh1 = (const float*)d_in[11];
    const float* bh1 = (const float*)d_in[12];
    const float* Wh2 = (const float*)d_in[13];
    const float* bh2 = (const float*)d_in[14];
    float* out = (float*)d_out;

    const int N = in_sizes[0] / 128;
    const int E = in_sizes[1] / 2;
    const int* src = ei;
    const int* dst = ei + E;

    // workspace: ints, then ushort arenas (hi,lo pairs)
    int* deg       = (int*)d_ws;            // N
    int* row_ptr   = deg + N;               // N+1
    int* cursor    = row_ptr + N + 1;       // N
    int* blockSums = cursor + N;            // <= 64
    int* col       = blockSums + 64;        // E
    size_t ioff = (((size_t)(3 * N + 1 + 64 + E)) * sizeof(int) + 255) & ~(size_t)255;
    unsigned short* u0H = (unsigned short*)((char*)d_ws + ioff);  // x pairs / hB pairs
    unsigned short* u0L = u0H + (size_t)N * 128;
    unsigned short* mH  = u0L + (size_t)N * 128;                  // mean pairs
    unsigned short* mL  = mH + (size_t)N * 128;
    unsigned short* aH  = mL + (size_t)N * 128;                   // hA pairs
    unsigned short* aL  = aH + (size_t)N * 128;
    unsigned short* WH  = aL + (size_t)N * 128;                   // 6 x 16384
    unsigned short* WL  = WH + 6 * 16384;

    const int eb = (E + 255) / 256;
    const int nb4 = (N + 3) / 4;
    const int gb64 = (N + 63) / 64;
    const int gb128 = (N + 127) / 128;
    const int sb = (N + 1023) / 1024;

    // CSR build
    hipMemsetAsync(deg, 0, (size_t)N * sizeof(int), stream);
    deg_count_kernel<<<eb, 256, 0, stream>>>(dst, E, deg);
    scan_partial_kernel<<<sb, 1024, 0, stream>>>(deg, N, row_ptr, blockSums);
    scan_sums_kernel<<<1, 64, 0, stream>>>(blockSums, sb, row_ptr, N);
    scan_add_kernel<<<(N + 255) / 256, 256, 0, stream>>>(row_ptr, cursor, blockSums, N);
    fill_kernel<<<eb, 256, 0, stream>>>(src, dst, E, cursor, col);

    // convert inputs to (hi,lo) pairs
    convert_x_kernel<<<(N * 32 + 255) / 256, 256, 0, stream>>>(x, u0H, u0L, N * 32);
    dim3 wgrid(16, 6);
    convert_w_kernel<<<wgrid, 256, 0, stream>>>(Wl0, Wr0, Wl1, Wr1, Wl2, Wr2, WH, WL);

    // layer 0: A0=mean(x), A1=x
    agg_mean_kernel<<<nb4, 256, 0, stream>>>(u0H, u0L, row_ptr, col, mH, mL, N);
    sage_gemm_mfma<<<gb128, 256, 0, stream>>>(mH, mL, u0H, u0L,
                                              WH + 0 * 16384, WL + 0 * 16384,
                                              WH + 1 * 16384, WL + 1 * 16384,
                                              bl0, aH, aL, N);
    // layer 1: A0=mean(hA), A1=hA -> u0 (x is dead)
    agg_mean_kernel<<<nb4, 256, 0, stream>>>(aH, aL, row_ptr, col, mH, mL, N);
    sage_gemm_mfma<<<gb128, 256, 0, stream>>>(mH, mL, aH, aL,
                                              WH + 2 * 16384, WL + 2 * 16384,
                                              WH + 3 * 16384, WL + 3 * 16384,
                                              bl1, u0H, u0L, N);
    // layer 2: A0=mean(hB), A1=hB -> hA
    agg_mean_kernel<<<nb4, 256, 0, stream>>>(u0H, u0L, row_ptr, col, mH, mL, N);
    sage_gemm_mfma<<<gb128, 256, 0, stream>>>(mH, mL, u0H, u0L,
                                              WH + 4 * 16384, WL + 4 * 16384,
                                              WH + 5 * 16384, WL + 5 * 16384,
                                              bl2, aH, aL, N);

    // fused head MLP (reads pairs)
    head_fused_kernel<<<gb64, 256, 0, stream>>>(aH, aL, Wh1, bh1, Wh2, bh2, out, N);
}

// Round 5
// 420.477 us; speedup vs baseline: 2.2469x; 1.1819x over previous
//
#include <hip/hip_runtime.h>
#include <cstdint>
#include <cstddef>

// ---------------------------------------------------------------------------
// StationGNN: 3x GraphSAGE(mean) + MLP head.
// R1: fused head MLP. R2: parallel scan. R3: split-bf16 MFMA GEMMs.
// R4: aggregation gathers hi(bf16)-only (halves gather bytes: 410->205 MB);
//     mean still accumulated fp32 and stored as (hi,lo). Gather unrolled x4.
// ---------------------------------------------------------------------------

typedef __attribute__((ext_vector_type(8))) short short8;
typedef __attribute__((ext_vector_type(8))) unsigned short ushort8;
typedef __attribute__((ext_vector_type(4))) float floatx4;

__device__ __forceinline__ float bf2f(unsigned short h) {
    return __uint_as_float(((unsigned int)h) << 16);
}
// truncation split: x ~= hi + lo with |x-hi-lo| <~ 2^-16 |x|
__device__ __forceinline__ void split2(float x, unsigned short& hi, unsigned short& lo) {
    unsigned int u = __float_as_uint(x);
    hi = (unsigned short)(u >> 16);
    float r = x - __uint_as_float(u & 0xFFFF0000u);
    lo = (unsigned short)(__float_as_uint(r) >> 16);
}

// ------------------------------ CSR build ----------------------------------

__global__ void deg_count_kernel(const int* __restrict__ dst, int E,
                                 int* __restrict__ deg) {
    int e = blockIdx.x * 256 + threadIdx.x;
    if (e < E) atomicAdd(&deg[dst[e]], 1);
}

__global__ __launch_bounds__(1024) void scan_partial_kernel(const int* __restrict__ deg,
                                                            int N, int* __restrict__ excl,
                                                            int* __restrict__ blockSums) {
    __shared__ int sdata[1024];
    int tid = threadIdx.x;
    int idx = blockIdx.x * 1024 + tid;
    int v = (idx < N) ? deg[idx] : 0;
    sdata[tid] = v;
    __syncthreads();
    for (int off = 1; off < 1024; off <<= 1) {
        int t = (tid >= off) ? sdata[tid - off] : 0;
        __syncthreads();
        sdata[tid] += t;
        __syncthreads();
    }
    if (idx < N) excl[idx] = sdata[tid] - v;
    if (tid == 1023) blockSums[blockIdx.x] = sdata[1023];
}

__global__ void scan_sums_kernel(int* __restrict__ blockSums, int nb,
                                 int* __restrict__ row_ptr, int N) {
    if (threadIdx.x == 0 && blockIdx.x == 0) {
        int run = 0;
        for (int i = 0; i < nb; ++i) { int t = blockSums[i]; blockSums[i] = run; run += t; }
        row_ptr[N] = run;
    }
}

__global__ void scan_add_kernel(int* __restrict__ row_ptr, int* __restrict__ cursor,
                                const int* __restrict__ blockSums, int N) {
    int idx = blockIdx.x * 256 + threadIdx.x;
    if (idx < N) {
        int v = row_ptr[idx] + blockSums[idx >> 10];
        row_ptr[idx] = v;
        cursor[idx] = v;
    }
}

__global__ void fill_kernel(const int* __restrict__ src, const int* __restrict__ dst,
                            int E, int* __restrict__ cursor, int* __restrict__ col) {
    int e = blockIdx.x * 256 + threadIdx.x;
    if (e < E) {
        int p = atomicAdd(&cursor[dst[e]], 1);
        col[p] = src[e];
    }
}

// --------------------------- fp32 -> (hi,lo) -------------------------------

__global__ void convert_x_kernel(const float* __restrict__ x,
                                 unsigned short* __restrict__ xH,
                                 unsigned short* __restrict__ xL, int total4) {
    int i = blockIdx.x * 256 + threadIdx.x;
    if (i >= total4) return;
    float4 v = ((const float4*)x)[i];
    unsigned short h0, h1, h2, h3, l0, l1, l2, l3;
    split2(v.x, h0, l0); split2(v.y, h1, l1); split2(v.z, h2, l2); split2(v.w, h3, l3);
    ((ushort4*)xH)[i] = make_ushort4(h0, h1, h2, h3);
    ((ushort4*)xL)[i] = make_ushort4(l0, l1, l2, l3);
}

// 6 weight matrices (128x128 each): Wl0,Wr0,Wl1,Wr1,Wl2,Wr2 -> segments of WH/WL
__global__ void convert_w_kernel(const float* __restrict__ w0, const float* __restrict__ w1,
                                 const float* __restrict__ w2, const float* __restrict__ w3,
                                 const float* __restrict__ w4, const float* __restrict__ w5,
                                 unsigned short* __restrict__ WH,
                                 unsigned short* __restrict__ WL) {
    int m = blockIdx.y;
    const float* src = (m == 0) ? w0 : (m == 1) ? w1 : (m == 2) ? w2
                       : (m == 3) ? w3 : (m == 4) ? w4 : w5;
    int i = blockIdx.x * 256 + threadIdx.x;       // float4 index, 4096 per matrix
    if (i >= 4096) return;
    float4 v = ((const float4*)src)[i];
    unsigned short h0, h1, h2, h3, l0, l1, l2, l3;
    split2(v.x, h0, l0); split2(v.y, h1, l1); split2(v.z, h2, l2); split2(v.w, h3, l3);
    ((ushort4*)(WH + (size_t)m * 16384))[i] = make_ushort4(h0, h1, h2, h3);
    ((ushort4*)(WL + (size_t)m * 16384))[i] = make_ushort4(l0, l1, l2, l3);
}

// ------------------------------ aggregation --------------------------------
// one wave per node; lane covers 2 features; gathers hi(bf16) ONLY (halved
// bytes); accumulates fp32; writes mean as (hi,lo) pair.
__global__ __launch_bounds__(256) void agg_mean_kernel(
    const unsigned short* __restrict__ inH,
    const int* __restrict__ row_ptr, const int* __restrict__ col,
    unsigned short* __restrict__ mH, unsigned short* __restrict__ mL, int N) {
    int wave = threadIdx.x >> 6;
    int lane = threadIdx.x & 63;
    int n = blockIdx.x * 4 + wave;
    if (n >= N) return;
    int beg = row_ptr[n];
    int end = row_ptr[n + 1];
    float ax = 0.f, ay = 0.f, bx = 0.f, by = 0.f;
    float cx = 0.f, cy = 0.f, dx = 0.f, dy = 0.f;
    int i = beg;
    for (; i + 3 < end; i += 4) {
        int s0 = col[i], s1 = col[i + 1], s2 = col[i + 2], s3 = col[i + 3];
        ushort2 h0 = ((const ushort2*)(inH + (size_t)s0 * 128))[lane];
        ushort2 h1 = ((const ushort2*)(inH + (size_t)s1 * 128))[lane];
        ushort2 h2 = ((const ushort2*)(inH + (size_t)s2 * 128))[lane];
        ushort2 h3 = ((const ushort2*)(inH + (size_t)s3 * 128))[lane];
        ax += bf2f(h0.x); ay += bf2f(h0.y);
        bx += bf2f(h1.x); by += bf2f(h1.y);
        cx += bf2f(h2.x); cy += bf2f(h2.y);
        dx += bf2f(h3.x); dy += bf2f(h3.y);
    }
    for (; i < end; ++i) {
        int s0 = col[i];
        ushort2 h0 = ((const ushort2*)(inH + (size_t)s0 * 128))[lane];
        ax += bf2f(h0.x); ay += bf2f(h0.y);
    }
    int d = end - beg;
    float inv = 1.0f / (float)(d > 0 ? d : 1);
    float vx = (ax + bx + cx + dx) * inv, vy = (ay + by + cy + dy) * inv;
    unsigned short hx, lx, hy, ly;
    split2(vx, hx, lx); split2(vy, hy, ly);
    ((ushort2*)(mH + (size_t)n * 128))[lane] = make_ushort2(hx, hy);
    ((ushort2*)(mL + (size_t)n * 128))[lane] = make_ushort2(lx, ly);
}

// ------------------------- split-bf16 MFMA GEMM ----------------------------
// out[n][j] = ReLU( sum_k A0[n][k] W0[j][k] + A1[n][k] W1[j][k] + bias[j] )
// 128 nodes x 128 outs per 256-thread block; 4 waves = 2x2 quadrants of 64x64.
__global__ __launch_bounds__(256, 2) void sage_gemm_mfma(
    const unsigned short* __restrict__ a0H, const unsigned short* __restrict__ a0L,
    const unsigned short* __restrict__ a1H, const unsigned short* __restrict__ a1L,
    const unsigned short* __restrict__ w0H, const unsigned short* __restrict__ w0L,
    const unsigned short* __restrict__ w1H, const unsigned short* __restrict__ w1L,
    const float* __restrict__ bias,
    unsigned short* __restrict__ outH, unsigned short* __restrict__ outL, int N) {
    __shared__ unsigned short Ah[128][40];
    __shared__ unsigned short Al[128][40];
    __shared__ unsigned short Wh[128][40];
    __shared__ unsigned short Wl[128][40];
    int tid = threadIdx.x;
    int n0 = blockIdx.x * 128;
    int wv = tid >> 6, lane = tid & 63;
    int wm = wv & 1, wn = wv >> 1;
    int r16 = lane & 15, q = lane >> 4, q8 = q * 8;

    floatx4 acc[4][4];
#pragma unroll
    for (int mi = 0; mi < 4; ++mi)
#pragma unroll
        for (int ni = 0; ni < 4; ++ni) {
            floatx4 z = {0.f, 0.f, 0.f, 0.f};
            acc[mi][ni] = z;
        }

    int tc = (tid & 3) * 8;
    int tr = tid >> 2;

    for (int part = 0; part < 2; ++part) {
        const unsigned short* AH = part ? a1H : a0H;
        const unsigned short* AL = part ? a1L : a0L;
        const unsigned short* WHp = part ? w1H : w0H;
        const unsigned short* WLp = part ? w1L : w0L;
        for (int kk = 0; kk < 128; kk += 32) {
            __syncthreads();
#pragma unroll
            for (int rr = 0; rr < 2; ++rr) {
                int row = tr + 64 * rr;
                int n = n0 + row;
                ushort8 vh = {0, 0, 0, 0, 0, 0, 0, 0};
                ushort8 vl = {0, 0, 0, 0, 0, 0, 0, 0};
                if (n < N) {
                    vh = *(const ushort8*)&AH[(size_t)n * 128 + kk + tc];
                    vl = *(const ushort8*)&AL[(size_t)n * 128 + kk + tc];
                }
                *(ushort8*)&Ah[row][tc] = vh;
                *(ushort8*)&Al[row][tc] = vl;
                *(ushort8*)&Wh[row][tc] = *(const ushort8*)&WHp[(size_t)row * 128 + kk + tc];
                *(ushort8*)&Wl[row][tc] = *(const ushort8*)&WLp[(size_t)row * 128 + kk + tc];
            }
            __syncthreads();
            short8 ah[4], al[4];
#pragma unroll
            for (int mi = 0; mi < 4; ++mi) {
                int row = 64 * wm + 16 * mi + r16;
                ah[mi] = *(const short8*)&Ah[row][q8];
                al[mi] = *(const short8*)&Al[row][q8];
            }
#pragma unroll
            for (int ni = 0; ni < 4; ++ni) {
                int row = 64 * wn + 16 * ni + r16;
                short8 bh = *(const short8*)&Wh[row][q8];
                short8 bl = *(const short8*)&Wl[row][q8];
#pragma unroll
                for (int mi = 0; mi < 4; ++mi) {
                    acc[mi][ni] = __builtin_amdgcn_mfma_f32_16x16x32_bf16(ah[mi], bh, acc[mi][ni], 0, 0, 0);
                    acc[mi][ni] = __builtin_amdgcn_mfma_f32_16x16x32_bf16(al[mi], bh, acc[mi][ni], 0, 0, 0);
                    acc[mi][ni] = __builtin_amdgcn_mfma_f32_16x16x32_bf16(ah[mi], bl, acc[mi][ni], 0, 0, 0);
                }
            }
        }
    }
#pragma unroll
    for (int ni = 0; ni < 4; ++ni) {
        int j = 64 * wn + 16 * ni + r16;
        float b = bias[j];
#pragma unroll
        for (int mi = 0; mi < 4; ++mi) {
            floatx4 v = acc[mi][ni];
#pragma unroll
            for (int p = 0; p < 4; ++p) {
                int node = n0 + 64 * wm + 16 * mi + 4 * q + p;
                if (node < N) {
                    float val = fmaxf(v[p] + b, 0.f);
                    unsigned short hi, lo;
                    split2(val, hi, lo);
                    outH[(size_t)node * 128 + j] = hi;
                    outL[(size_t)node * 128 + j] = lo;
                }
            }
        }
    }
}

// ------------------------------ fused head ---------------------------------
__global__ __launch_bounds__(256) void head_fused_kernel(
    const unsigned short* __restrict__ hH, const unsigned short* __restrict__ hL,
    const float* __restrict__ Wh1, const float* __restrict__ bh1,
    const float* __restrict__ Wh2, const float* __restrict__ bh2,
    float* __restrict__ out, int N) {
    __shared__ float As[64][33];
    __shared__ float Bs[32][65];
    __shared__ float Hs[64][65];
    int tid = threadIdx.x;
    int n0 = blockIdx.x * 64;
    int ti = tid & 15;
    int tj = tid >> 4;

    float acc[4][4];
#pragma unroll
    for (int r = 0; r < 4; ++r)
#pragma unroll
        for (int c = 0; c < 4; ++c) acc[r][c] = 0.f;

    for (int kk = 0; kk < 128; kk += 32) {
        int ks = tid & 31, i0 = tid >> 5;
#pragma unroll
        for (int r = 0; r < 8; ++r) {
            int i = i0 + 8 * r;
            int n = n0 + i;
            As[i][ks] = (n < N)
                ? (bf2f(hH[(size_t)n * 128 + kk + ks]) + bf2f(hL[(size_t)n * 128 + kk + ks]))
                : 0.f;
        }
        int jj0 = tid >> 5;
#pragma unroll
        for (int r = 0; r < 8; ++r) {
            int j = jj0 + 8 * r;
            Bs[ks][j] = Wh1[(size_t)j * 128 + kk + ks];
        }
        __syncthreads();
#pragma unroll 4
        for (int k = 0; k < 32; ++k) {
            float4 b = *(const float4*)&Bs[k][4 * tj];
#pragma unroll
            for (int r = 0; r < 4; ++r) {
                float a = As[4 * ti + r][k];
                acc[r][0] += a * b.x; acc[r][1] += a * b.y;
                acc[r][2] += a * b.z; acc[r][3] += a * b.w;
            }
        }
        __syncthreads();
    }
    float4 bv = *(const float4*)&bh1[4 * tj];
#pragma unroll
    for (int r = 0; r < 4; ++r) {
        int i = 4 * ti + r;
        Hs[i][4 * tj + 0] = fmaxf(acc[r][0] + bv.x, 0.f);
        Hs[i][4 * tj + 1] = fmaxf(acc[r][1] + bv.y, 0.f);
        Hs[i][4 * tj + 2] = fmaxf(acc[r][2] + bv.z, 0.f);
        Hs[i][4 * tj + 3] = fmaxf(acc[r][3] + bv.w, 0.f);
    }
    __syncthreads();
    int ni = tid >> 2;
    int c = tid & 3;
    const float* w = Wh2 + (size_t)c * 64;
    float s = bh2[c];
#pragma unroll 8
    for (int k = 0; k < 64; ++k) s += Hs[ni][k] * w[k];
    int n = n0 + ni;
    if (n < N) out[(size_t)n * 4 + c] = s;
}

// ------------------------------- launcher ----------------------------------

extern "C" void kernel_launch(void* const* d_in, const int* in_sizes, int n_in,
                              void* d_out, int out_size, void* d_ws, size_t ws_size,
                              hipStream_t stream) {
    const float* x   = (const float*)d_in[0];
    const int*   ei  = (const int*)d_in[1];
    const float* Wl0 = (const float*)d_in[2];
    const float* bl0 = (const float*)d_in[3];
    const float* Wr0 = (const float*)d_in[4];
    const float* Wl1 = (const float*)d_in[5];
    const float* bl1 = (const float*)d_in[6];
    const float* Wr1 = (const float*)d_in[7];
    const float* Wl2 = (const float*)d_in[8];
    const float* bl2 = (const float*)d_in[9];
    const float* Wr2 = (const float*)d_in[10];
    const float* Wh1 = (const float*)d_in[11];
    const float* bh1 = (const float*)d_in[12];
    const float* Wh2 = (const float*)d_in[13];
    const float* bh2 = (const float*)d_in[14];
    float* out = (float*)d_out;

    const int N = in_sizes[0] / 128;
    const int E = in_sizes[1] / 2;
    const int* src = ei;
    const int* dst = ei + E;

    int* deg       = (int*)d_ws;            // N
    int* row_ptr   = deg + N;               // N+1
    int* cursor    = row_ptr + N + 1;       // N
    int* blockSums = cursor + N;            // <= 64
    int* col       = blockSums + 64;        // E
    size_t ioff = (((size_t)(3 * N + 1 + 64 + E)) * sizeof(int) + 255) & ~(size_t)255;
    unsigned short* u0H = (unsigned short*)((char*)d_ws + ioff);  // x pairs / hB pairs
    unsigned short* u0L = u0H + (size_t)N * 128;
    unsigned short* mH  = u0L + (size_t)N * 128;                  // mean pairs
    unsigned short* mL  = mH + (size_t)N * 128;
    unsigned short* aH  = mL + (size_t)N * 128;                   // hA pairs
    unsigned short* aL  = aH + (size_t)N * 128;
    unsigned short* WH  = aL + (size_t)N * 128;                   // 6 x 16384
    unsigned short* WL  = WH + 6 * 16384;

    const int eb = (E + 255) / 256;
    const int nb4 = (N + 3) / 4;
    const int gb64 = (N + 63) / 64;
    const int gb128 = (N + 127) / 128;
    const int sb = (N + 1023) / 1024;

    // CSR build
    hipMemsetAsync(deg, 0, (size_t)N * sizeof(int), stream);
    deg_count_kernel<<<eb, 256, 0, stream>>>(dst, E, deg);
    scan_partial_kernel<<<sb, 1024, 0, stream>>>(deg, N, row_ptr, blockSums);
    scan_sums_kernel<<<1, 64, 0, stream>>>(blockSums, sb, row_ptr, N);
    scan_add_kernel<<<(N + 255) / 256, 256, 0, stream>>>(row_ptr, cursor, blockSums, N);
    fill_kernel<<<eb, 256, 0, stream>>>(src, dst, E, cursor, col);

    // convert inputs to (hi,lo) pairs
    convert_x_kernel<<<(N * 32 + 255) / 256, 256, 0, stream>>>(x, u0H, u0L, N * 32);
    dim3 wgrid(16, 6);
    convert_w_kernel<<<wgrid, 256, 0, stream>>>(Wl0, Wr0, Wl1, Wr1, Wl2, Wr2, WH, WL);

    // layer 0: A0=mean(x), A1=x
    agg_mean_kernel<<<nb4, 256, 0, stream>>>(u0H, row_ptr, col, mH, mL, N);
    sage_gemm_mfma<<<gb128, 256, 0, stream>>>(mH, mL, u0H, u0L,
                                              WH + 0 * 16384, WL + 0 * 16384,
                                              WH + 1 * 16384, WL + 1 * 16384,
                                              bl0, aH, aL, N);
    // layer 1
    agg_mean_kernel<<<nb4, 256, 0, stream>>>(aH, row_ptr, col, mH, mL, N);
    sage_gemm_mfma<<<gb128, 256, 0, stream>>>(mH, mL, aH, aL,
                                              WH + 2 * 16384, WL + 2 * 16384,
                                              WH + 3 * 16384, WL + 3 * 16384,
                                              bl1, u0H, u0L, N);
    // layer 2
    agg_mean_kernel<<<nb4, 256, 0, stream>>>(u0H, row_ptr, col, mH, mL, N);
    sage_gemm_mfma<<<gb128, 256, 0, stream>>>(mH, mL, u0H, u0L,
                                              WH + 4 * 16384, WL + 4 * 16384,
                                              WH + 5 * 16384, WL + 5 * 16384,
                                              bl2, aH, aL, N);

    // fused head MLP
    head_fused_kernel<<<gb64, 256, 0, stream>>>(aH, aL, Wh1, bh1, Wh2, bh2, out, N);
}